// Round 6
// baseline (208.807 us; speedup 1.0000x reference)
//
#include <hip/hip_runtime.h>
#include <hip/hip_bf16.h>
#include <stdint.h>

// Shape fixed by reference: B=2, S=1024 -> M=2048; N=4096; K=4096
#define M_DIM 2048
#define N_DIM 4096
#define K_DIM 4096

#define BM 128
#define BN 128
#define BK 128            // int8 elements per K-tile = 128 B per row

#define BTILE (BN * BK)   // 16 KiB per B buffer
#define NT (K_DIM / BK)   // 32 K-tiles

typedef __attribute__((ext_vector_type(4))) int   int4v;
typedef __attribute__((ext_vector_type(4))) float f32x4;

__device__ __forceinline__ void load_lds16(const void* g, void* l) {
    __builtin_amdgcn_global_load_lds(
        (const __attribute__((address_space(1))) void*)g,
        (__attribute__((address_space(3))) void*)l,
        16, 0, 0);
}

// ---------- x: fp32 [M,K] -> int8 per-row dynamic quant; sx[row] = rowmax/127 ----------
__global__ __launch_bounds__(256) void quant_x(const float* __restrict__ x,
                                               int8_t* __restrict__ Aq,
                                               float* __restrict__ sx) {
    const int row = blockIdx.x;
    const int tid = threadIdx.x;
    const float4* xr = (const float4*)(x + (size_t)row * K_DIM);

    float4 v[4];
    float mx = 0.f;
#pragma unroll
    for (int p = 0; p < 4; p++) {
        v[p] = xr[p * 256 + tid];
        mx = fmaxf(mx, fmaxf(fmaxf(fabsf(v[p].x), fabsf(v[p].y)),
                             fmaxf(fabsf(v[p].z), fabsf(v[p].w))));
    }
#pragma unroll
    for (int off = 32; off >= 1; off >>= 1)
        mx = fmaxf(mx, __shfl_xor(mx, off, 64));

    __shared__ float wmax[4];
    __shared__ float smax;
    if ((tid & 63) == 0) wmax[tid >> 6] = mx;
    __syncthreads();
    if (tid == 0) {
        float m = fmaxf(fmaxf(wmax[0], wmax[1]), fmaxf(wmax[2], wmax[3]));
        m = fmaxf(m, 1e-20f);
        smax = m;
        sx[row] = m * (1.0f / 127.0f);
    }
    __syncthreads();
    const float inv = 127.0f / smax;

    int* out = (int*)Aq + (size_t)row * (K_DIM / 4);
#pragma unroll
    for (int p = 0; p < 4; p++) {
        int q0 = (int)__builtin_rintf(v[p].x * inv);
        int q1 = (int)__builtin_rintf(v[p].y * inv);
        int q2 = (int)__builtin_rintf(v[p].z * inv);
        int q3 = (int)__builtin_rintf(v[p].w * inv);
        q0 = max(-127, min(127, q0)); q1 = max(-127, min(127, q1));
        q2 = max(-127, min(127, q2)); q3 = max(-127, min(127, q3));
        out[p * 256 + tid] = (q0 & 255) | ((q1 & 255) << 8) |
                             ((q2 & 255) << 16) | ((q3 & 255) << 24);
    }
}

// ---------- w: int32 [N,K] (values in [-128,127]) -> int8, exact narrowing ----------
__global__ __launch_bounds__(256) void cvt_w8(const int* __restrict__ w,
                                              int8_t* __restrict__ Bq) {
    size_t i = ((size_t)blockIdx.x * 256 + threadIdx.x) * 16;
    int4 a0 = *(const int4*)(w + i);
    int4 a1 = *(const int4*)(w + i + 4);
    int4 a2 = *(const int4*)(w + i + 8);
    int4 a3 = *(const int4*)(w + i + 12);
    uint4 t;
    t.x = (a0.x & 255) | ((a0.y & 255) << 8) | ((a0.z & 255) << 16) | ((a0.w & 255) << 24);
    t.y = (a1.x & 255) | ((a1.y & 255) << 8) | ((a1.z & 255) << 16) | ((a1.w & 255) << 24);
    t.z = (a2.x & 255) | ((a2.y & 255) << 8) | ((a2.z & 255) << 16) | ((a2.w & 255) << 24);
    t.w = (a3.x & 255) | ((a3.y & 255) << 8) | ((a3.z & 255) << 16) | ((a3.w & 255) << 24);
    *(uint4*)(Bq + i) = t;
}

// ---------- GEMM: C = Aq[M,K] x Bq[N,K]^T (i8 MFMA, i32 acc), epilogue dequant ----------
// r10: r9's verified shell (128x128 block, 512 thr, K-split 4 spatial waves x 2,
// 2 blocks/CU, 16 waves/CU) with A moved from LDS staging to direct global->VGPR.
// Post-mortem model: r4 and r9 both pin at ~3050 cyc/tile while moving 128 KB/CU/
// tile through the glds staging path (L2 fetch + LDS write) -- r9's 33% LDS-READ
// cut bought nothing, so staged BYTES, not read bytes, are the invariant. Halve
// staging: B stays on the byte-identical r9 glds+XOR-swizzle path (64 KB/CU/tile);
// A fragments load straight to registers. Under K-split each wave needs only 4
// A-frags/tile = 16 VGPR; dbuf afA/afB = 32 live (r8 died with 64 + no K-split).
// A bytes match the swizzled-LDS-read bytes exactly:
//   af[i] = A[bm*128 + wm + i*16 + l16][k0 + ks*64 + quad*16 .. +15]
// (r9's cp^(row&7) cancellation delivered the same identity k-chunks), so the
// arithmetic is unchanged from the passing r9 kernel. A-loads are 16x64B fully-
// consumed segments, L1-dedup'd across the two waves sharing each wm group; they
// are issued one full tile ahead and the existing __syncthreads vmcnt drain
// guarantees arrival. LDS = Bs dbuf 32 KB + 32 KB reduction scratch = 64 KB
// (same footprint as r9 -> occupancy unchanged). Register budget: ~60 VGPR +
// 64 AGPR acc = ~124/wave < 128 cap at launch_bounds(512,4).

__global__ __launch_bounds__(512, 4) void gemm_bt_i8(
    const int8_t* __restrict__ A,      // [M,K] int8
    const int8_t* __restrict__ B,      // [N,K] int8
    const float*  __restrict__ sx,     // [M] row dequant scale
    const float*  __restrict__ scales, // [N]
    const float*  __restrict__ bias,   // [N]
    float* __restrict__ C)             // [M,N]
{
    __shared__ __align__(16) int8_t Bs[2 * BTILE];  // 32 KiB (B dbuf)
    __shared__ __align__(16) int8_t Rs[32768];      // 32 KiB (K-split reduction)

    const int tid  = threadIdx.x;

    // T1: XCD-aware swizzle. 512 blocks = 8 chunks of 64; chunk = 8(bm) x 8(bn).
    const int bid   = blockIdx.x;
    const int xcd   = bid & 7;
    const int local = bid >> 3;                       // 0..63
    const int bm    = (xcd >> 2) * 8 + (local >> 3);  // 0..15
    const int bn    = (xcd & 3) * 8 + (local & 7);    // 0..31

    const int lane = tid & 63;
    const int wave = tid >> 6;           // 0..7
    const int spat = wave & 3;           // spatial 2x2
    const int ks   = wave >> 2;          // K-split half: 0 or 1
    const int wm   = (spat >> 1) * 64;   // 0 or 64
    const int wn   = (spat & 1) * 64;    // 0 or 64
    const int l16  = lane & 15;
    const int quad = lane >> 4;
    const int swz  = l16 & 7;
    // Fixed physical colgroup for this wave's k-half (r9 verified formula).
    const int cp   = (ks * 4 + quad) ^ swz;

    // B staging (r9 scheme, byte-identical): 512 thr x 16 B = 8 KiB/instr;
    // 2 instrs per 16 KiB tile. thread t -> row = t>>3 (+64 for seg1), phys
    // colgroup = t&7; global colgroup = phys ^ (row&7). LDS byte addr = 16*t.
    const int srow = tid >> 3;           // 0..63
    const int cgl  = (tid & 7) ^ (srow & 7);

    const int8_t* gb0 = B + (size_t)(bn * BN + srow)      * K_DIM + cgl * 16;
    const int8_t* gb1 = B + (size_t)(bn * BN + 64 + srow) * K_DIM + cgl * 16;
    const int la0 = tid * 16;
    const int la1 = 8192 + tid * 16;

    // A direct-to-reg: lane (l16,quad) of wave (spat,ks) reads
    // row bm*128 + wm + i*16 + l16, bytes k0 + ks*64 + quad*16 (identity k-order).
    const int8_t* Ap = A + (size_t)(bm * BM + wm + l16) * K_DIM + ks * 64 + quad * 16;

    int4v afA[4], afB[4];
    int4v acc[4][4] = {};

#define PREA(dst, k0_) do {                                                  \
        _Pragma("unroll")                                                    \
        for (int i = 0; i < 4; i++)                                          \
            dst[i] = *(const int4v*)(Ap + (k0_) + i * (16 * K_DIM));         \
    } while (0)

#define STAGEB(slot, k0_) do {                                               \
        load_lds16(gb0 + (k0_), Bs + (slot) * BTILE + la0);                  \
        load_lds16(gb1 + (k0_), Bs + (slot) * BTILE + la1);                  \
    } while (0)

#define COMP(af, slot) do {                                                  \
        const int8_t* Bb = Bs + (slot) * BTILE;                              \
        _Pragma("unroll")                                                    \
        for (int j = 0; j < 4; j++) {                                        \
            int4v bf = *(const int4v*)(Bb + (wn + j * 16 + l16) * BK + cp * 16); \
            _Pragma("unroll")                                                \
            for (int i = 0; i < 4; i++)                                      \
                acc[i][j] = __builtin_amdgcn_mfma_i32_16x16x64_i8(           \
                    af[i], bf, acc[i][j], 0, 0, 0);                          \
        }                                                                    \
    } while (0)

    // Prologue: tile 0 -> B LDS buf0 + A regs afA.
    PREA(afA, 0);
    STAGEB(0, 0);

    for (int t = 0; t < NT; t += 2) {
        __syncthreads();                 // drains: B(t) staged, afA loaded
        STAGEB(1, (t + 1) * BK);         // prefetch tile t+1 (t+1 <= 31 always)
        PREA(afB, (t + 1) * BK);
        COMP(afA, 0);

        __syncthreads();                 // drains: B(t+1) staged, afB loaded
        if (t + 2 < NT) {
            STAGEB(0, (t + 2) * BK);
            PREA(afA, (t + 2) * BK);
        }
        COMP(afB, 1);
    }

#undef PREA
#undef STAGEB
#undef COMP

    // ---- K-split reduction: ks=1 waves dump acc to LDS, ks=0 waves add ----
    __syncthreads();   // all K-loop LDS reads complete -> Bs reusable

    // 16 KiB per spatial wave: spat 0,1 -> Bs halves; spat 2,3 -> Rs halves.
    int8_t* rbase = (spat < 2 ? Bs : Rs) + (spat & 1) * 16384;

    if (ks == 1) {
#pragma unroll
        for (int i = 0; i < 4; i++)
#pragma unroll
            for (int j = 0; j < 4; j++)
                *(int4v*)(rbase + ((i * 4 + j) * 64 + lane) * 16) = acc[i][j];
    }
    __syncthreads();

    if (ks == 0) {
#pragma unroll
        for (int i = 0; i < 4; i++)
#pragma unroll
            for (int j = 0; j < 4; j++)
                acc[i][j] += *(const int4v*)(rbase + ((i * 4 + j) * 64 + lane) * 16);

        // Row dequant scales for this lane's 16 output rows.
        float sxr[16];
#pragma unroll
        for (int i = 0; i < 4; i++)
#pragma unroll
            for (int r = 0; r < 4; r++)
                sxr[i * 4 + r] = sx[bm * BM + wm + i * 16 + quad * 4 + r];

        // C/D layout (shape-determined, verified): col = lane&15, row = quad*4 + reg.
#pragma unroll
        for (int j = 0; j < 4; j++) {
            const int col = bn * BN + wn + j * 16 + l16;
            const float s = scales[col];
            const float b = bias[col];
#pragma unroll
            for (int i = 0; i < 4; i++) {
                const int row0 = bm * BM + wm + i * 16 + quad * 4;
#pragma unroll
                for (int r = 0; r < 4; r++) {
                    C[(size_t)(row0 + r) * N_DIM + col] =
                        (float)acc[i][j][r] * (sxr[i * 4 + r] * s) + b;
                }
            }
        }
    }
}

// ---------- launch ----------

extern "C" void kernel_launch(void* const* d_in, const int* in_sizes, int n_in,
                              void* d_out, int out_size, void* d_ws, size_t ws_size,
                              hipStream_t stream) {
    const float* x      = (const float*)d_in[0];   // [2,1024,4096] fp32
    const int*   w      = (const int*)d_in[1];     // [4096,4096] int, values in [-128,127]
    const float* scales = (const float*)d_in[2];   // [4096]
    const float* bias   = (const float*)d_in[3];   // [4096]
    float*       out    = (float*)d_out;           // [2,1024,4096] fp32

    int8_t* Aq = (int8_t*)d_ws;                                        // 8 MiB
    int8_t* Bq = (int8_t*)d_ws + (size_t)M_DIM * K_DIM;                // 16 MiB
    float*  sx = (float*)((int8_t*)d_ws + (size_t)(M_DIM + N_DIM) * K_DIM); // 8 KiB

    quant_x<<<M_DIM, 256, 0, stream>>>(x, Aq, sx);
    cvt_w8<<<(int)((size_t)N_DIM * K_DIM / 16 / 256), 256, 0, stream>>>(w, Bq);

    // 1-D grid of 512 blocks (16 bm x 32 bn), XCD-swizzled inside the kernel.
    gemm_bt_i8<<<512, 512, 0, stream>>>(Aq, Bq, sx, scales, bias, out);
}

// Round 7
// 169.393 us; speedup vs baseline: 1.2327x; 1.2327x over previous
//
#include <hip/hip_runtime.h>
#include <hip/hip_bf16.h>
#include <stdint.h>

// Shape fixed by reference: B=2, S=1024 -> M=2048; N=4096; K=4096
#define M_DIM 2048
#define N_DIM 4096
#define K_DIM 4096

#define BM 128
#define BN 256
#define BK 128            // int8 elements per K-tile = 128 B per row

#define NSLOT 3           // ring -> 2-deep prefetch -> counted vmcnt(6)
#define ASLOT (BM * BK)   // 16 KiB per A slot
#define BSLOT (BN * BK)   // 32 KiB per B slot
#define NT (K_DIM / BK)   // 32 K-tiles

typedef __attribute__((ext_vector_type(4))) int   int4v;
typedef __attribute__((ext_vector_type(4))) float f32x4;

__device__ __forceinline__ void load_lds16(const void* g, void* l) {
    __builtin_amdgcn_global_load_lds(
        (const __attribute__((address_space(1))) void*)g,
        (__attribute__((address_space(3))) void*)l,
        16, 0, 0);
}

// ---------- x: fp32 [M,K] -> int8 per-row dynamic quant; sx[row] = rowmax/127 ----------
__global__ __launch_bounds__(256) void quant_x(const float* __restrict__ x,
                                               int8_t* __restrict__ Aq,
                                               float* __restrict__ sx) {
    const int row = blockIdx.x;
    const int tid = threadIdx.x;
    const float4* xr = (const float4*)(x + (size_t)row * K_DIM);

    float4 v[4];
    float mx = 0.f;
#pragma unroll
    for (int p = 0; p < 4; p++) {
        v[p] = xr[p * 256 + tid];
        mx = fmaxf(mx, fmaxf(fmaxf(fabsf(v[p].x), fabsf(v[p].y)),
                             fmaxf(fabsf(v[p].z), fabsf(v[p].w))));
    }
#pragma unroll
    for (int off = 32; off >= 1; off >>= 1)
        mx = fmaxf(mx, __shfl_xor(mx, off, 64));

    __shared__ float wmax[4];
    __shared__ float smax;
    if ((tid & 63) == 0) wmax[tid >> 6] = mx;
    __syncthreads();
    if (tid == 0) {
        float m = fmaxf(fmaxf(wmax[0], wmax[1]), fmaxf(wmax[2], wmax[3]));
        m = fmaxf(m, 1e-20f);
        smax = m;
        sx[row] = m * (1.0f / 127.0f);
    }
    __syncthreads();
    const float inv = 127.0f / smax;

    int* out = (int*)Aq + (size_t)row * (K_DIM / 4);
#pragma unroll
    for (int p = 0; p < 4; p++) {
        int q0 = (int)__builtin_rintf(v[p].x * inv);
        int q1 = (int)__builtin_rintf(v[p].y * inv);
        int q2 = (int)__builtin_rintf(v[p].z * inv);
        int q3 = (int)__builtin_rintf(v[p].w * inv);
        q0 = max(-127, min(127, q0)); q1 = max(-127, min(127, q1));
        q2 = max(-127, min(127, q2)); q3 = max(-127, min(127, q3));
        out[p * 256 + tid] = (q0 & 255) | ((q1 & 255) << 8) |
                             ((q2 & 255) << 16) | ((q3 & 255) << 24);
    }
}

// ---------- w: int32 [N,K] (values in [-128,127]) -> int8, exact narrowing ----------
__global__ __launch_bounds__(256) void cvt_w8(const int* __restrict__ w,
                                              int8_t* __restrict__ Bq) {
    size_t i = ((size_t)blockIdx.x * 256 + threadIdx.x) * 16;
    int4 a0 = *(const int4*)(w + i);
    int4 a1 = *(const int4*)(w + i + 4);
    int4 a2 = *(const int4*)(w + i + 8);
    int4 a3 = *(const int4*)(w + i + 12);
    uint4 t;
    t.x = (a0.x & 255) | ((a0.y & 255) << 8) | ((a0.z & 255) << 16) | ((a0.w & 255) << 24);
    t.y = (a1.x & 255) | ((a1.y & 255) << 8) | ((a1.z & 255) << 16) | ((a1.w & 255) << 24);
    t.z = (a2.x & 255) | ((a2.y & 255) << 8) | ((a2.z & 255) << 16) | ((a2.w & 255) << 24);
    t.w = (a3.x & 255) | ((a3.y & 255) << 8) | ((a3.z & 255) << 16) | ((a3.w & 255) << 24);
    *(uint4*)(Bq + i) = t;
}

// ---------- GEMM: C = Aq[M,K] x Bq[N,K]^T (i8 MFMA, i32 acc), epilogue dequant ----------
// r11: m201 8-phase template ported to i8 (T2+T3+T4+T5+T1 full stack).
// Post-mortem chain: r9 falsified LDS-read-bound; r10 falsified staged-bytes-bound;
// what remains (and matches m233's measurement of this exact structure) is the
// 2-phase barrier convoy: drain-to-0 + burst-read + MFMA-ramp per tile. m196/m201:
// the fix needs the FINE per-phase interleave, not just counted vmcnt (r6's coarse
// variant failed as m196 predicts).
// Geometry: 128x256 tile, BK=128, grid 16x16=256 blocks (1 per CU), 512 thr,
// 8 waves (2Mx4N) each 64x64 out (acc[4][4]). Ring of 3 LDS slots (144 KiB,
// LDS-bound 1 block/CU, 2 waves/SIMD -- m201's proven regime). Per K-tile,
// 2 phases matching m201's per-phase shape {8 ds_read_b128, 3 glds, 16 MFMA}:
//   phase(h): ds_read af[4],bf[4] for k-half h; issue 3 glds of tile t+2;
//             s_barrier; lgkmcnt(0); setprio(1); 16 MFMA; setprio(0); s_barrier
// Counted vmcnt(6) once per K-tile (before phase-1's first barrier): tile t+1's
// 6 loads (issued during t-1) proven done; t+2's 6 stay in flight across the
// barrier -- never drained in the main loop.
// Slot-reuse safety: staging targets slot (t+2)%3 == (t-1)%3, whose reads all
// completed before tile t-1's closing barrier (lgkm waits precede the MFMAs).
// Data path byte-identical to verified r4/r9: XOR-swizzled glds source (phys
// colgroup p of row r holds global cg p^(r&7)); read cp=(h*4+quad)^(l16&7)
// cancels to identity k-chunks; 0 bank conflicts measured.

__global__ __launch_bounds__(512) void gemm_bt_i8(
    const int8_t* __restrict__ A,      // [M,K] int8
    const int8_t* __restrict__ B,      // [N,K] int8
    const float*  __restrict__ sx,     // [M] row dequant scale
    const float*  __restrict__ scales, // [N]
    const float*  __restrict__ bias,   // [N]
    float* __restrict__ C)             // [M,N]
{
    __shared__ __align__(16) int8_t As[NSLOT * ASLOT];  // 48 KiB
    __shared__ __align__(16) int8_t Bs[NSLOT * BSLOT];  // 96 KiB

    const int tid  = threadIdx.x;

    // T1: XCD swizzle. 256 blocks = 8 chunks of 32; chunk = 4(bm) x 8(bn).
    // Per-XCD working set per K-step: 4 A-tiles (64KB) + 8 B-tiles (256KB) << 4MB L2.
    const int bid   = blockIdx.x;
    const int xcd   = bid & 7;
    const int local = bid >> 3;                       // 0..31
    const int bm    = (xcd >> 1) * 4 + (local >> 3);  // 0..15
    const int bn    = (xcd & 1) * 8 + (local & 7);    // 0..15

    const int lane = tid & 63;
    const int wave = tid >> 6;           // 0..7
    const int wm   = (wave >> 2) * 64;   // 0 or 64      (A rows within 128)
    const int wn   = (wave & 3) * 64;    // 0,64,128,192 (B rows within 256)
    const int l16  = lane & 15;
    const int quad = lane >> 4;
    const int swz  = l16 & 7;

    // Staging (verified scheme): 512 thr x 16 B = 8 KiB per glds instr.
    // A slot = 2 segs (rows 0-63, 64-127); B slot = 4 segs. thread t -> seg row
    // = t>>3, phys colgroup = t&7; global colgroup = phys ^ (row&7); LDS byte
    // addr = seg*8192 + 16*t (linear in tid per instr -- glds rule).
    const int srow = tid >> 3;           // 0..63
    const int cgl  = (tid & 7) ^ (srow & 7);

    const int8_t* ga0 = A + (size_t)(bm * BM + srow)       * K_DIM + cgl * 16;
    const int8_t* ga1 = A + (size_t)(bm * BM + 64 + srow)  * K_DIM + cgl * 16;
    const int8_t* gb0 = B + (size_t)(bn * BN + srow)       * K_DIM + cgl * 16;
    const int8_t* gb1 = B + (size_t)(bn * BN + 64 + srow)  * K_DIM + cgl * 16;
    const int8_t* gb2 = B + (size_t)(bn * BN + 128 + srow) * K_DIM + cgl * 16;
    const int8_t* gb3 = B + (size_t)(bn * BN + 192 + srow) * K_DIM + cgl * 16;
    const int la = tid * 16;

    // First 3 loads of a tile (phase 0): A seg0, A seg1, B seg0.
#define STAGE1(slot, k0_) do {                                               \
        load_lds16(ga0 + (k0_), As + (slot) * ASLOT + la);                   \
        load_lds16(ga1 + (k0_), As + (slot) * ASLOT + 8192 + la);            \
        load_lds16(gb0 + (k0_), Bs + (slot) * BSLOT + la);                   \
    } while (0)
    // Remaining 3 (phase 1): B segs 1,2,3.
#define STAGE2(slot, k0_) do {                                               \
        load_lds16(gb1 + (k0_), Bs + (slot) * BSLOT + 8192 + la);            \
        load_lds16(gb2 + (k0_), Bs + (slot) * BSLOT + 16384 + la);           \
        load_lds16(gb3 + (k0_), Bs + (slot) * BSLOT + 24576 + la);           \
    } while (0)

    int4v acc[4][4] = {};

    // One phase: {8 ds_read | stage | [vmcnt]} -> barrier -> lgkm0 -> 16 MFMA -> barrier.
#define PHASE(h_, Ab, Bb, STG, VMW) do {                                     \
        const int cp_ = ((h_) * 4 + quad) ^ swz;                             \
        int4v af[4], bf[4];                                                  \
        _Pragma("unroll")                                                    \
        for (int i = 0; i < 4; i++)                                          \
            af[i] = *(const int4v*)((Ab) + (wm + i * 16 + l16) * BK + cp_ * 16); \
        _Pragma("unroll")                                                    \
        for (int j = 0; j < 4; j++)                                          \
            bf[j] = *(const int4v*)((Bb) + (wn + j * 16 + l16) * BK + cp_ * 16); \
        STG;                                                                 \
        VMW;                                                                 \
        __builtin_amdgcn_s_barrier();                                        \
        asm volatile("s_waitcnt lgkmcnt(0)" ::: "memory");                   \
        __builtin_amdgcn_s_setprio(1);                                       \
        _Pragma("unroll")                                                    \
        for (int j = 0; j < 4; j++)                                          \
            _Pragma("unroll")                                                \
            for (int i = 0; i < 4; i++)                                      \
                acc[i][j] = __builtin_amdgcn_mfma_i32_16x16x64_i8(           \
                    af[i], bf[j], acc[i][j], 0, 0, 0);                       \
        __builtin_amdgcn_s_setprio(0);                                       \
        __builtin_amdgcn_s_barrier();                                        \
    } while (0)

    // Prologue: tiles 0 and 1 staged (12 loads in flight).
    STAGE1(0, 0);      STAGE2(0, 0);
    STAGE1(1, BK);     STAGE2(1, BK);
    asm volatile("s_waitcnt vmcnt(6)" ::: "memory");   // tile 0 done, tile 1 in flight
    __builtin_amdgcn_s_barrier();

    int s0 = 0, s1 = 1, s2 = 2;   // slots of tiles t, t+1, t+2
    for (int t = 0; t < NT; ++t) {
        const int8_t* Ab = As + s0 * ASLOT;
        const int8_t* Bb = Bs + s0 * BSLOT;
        const int kf = (t + 2) * BK;
        if (t + 2 < NT) {
            PHASE(0, Ab, Bb, STAGE1(s2, kf), (void)0);
            PHASE(1, Ab, Bb, STAGE2(s2, kf),
                  asm volatile("s_waitcnt vmcnt(6)" ::: "memory"));
        } else {
            // No staging left; drain so tile t+1 (if any) is ready.
            PHASE(0, Ab, Bb, (void)0, (void)0);
            PHASE(1, Ab, Bb, (void)0,
                  asm volatile("s_waitcnt vmcnt(0)" ::: "memory"));
        }
        const int tmp = s0; s0 = s1; s1 = s2; s2 = tmp;
    }

#undef PHASE
#undef STAGE1
#undef STAGE2

    // Row dequant scales for this lane's 16 output rows.
    float sxr[16];
#pragma unroll
    for (int i = 0; i < 4; i++)
#pragma unroll
        for (int r = 0; r < 4; r++)
            sxr[i * 4 + r] = sx[bm * BM + wm + i * 16 + quad * 4 + r];

    // Epilogue. C/D layout (shape-determined, verified): col = lane&15, row = quad*4 + reg.
#pragma unroll
    for (int j = 0; j < 4; j++) {
        const int col = bn * BN + wn + j * 16 + l16;
        const float s = scales[col];
        const float b = bias[col];
#pragma unroll
        for (int i = 0; i < 4; i++) {
            const int row0 = bm * BM + wm + i * 16 + quad * 4;
#pragma unroll
            for (int r = 0; r < 4; r++) {
                C[(size_t)(row0 + r) * N_DIM + col] =
                    (float)acc[i][j][r] * (sxr[i * 4 + r] * s) + b;
            }
        }
    }
}

// ---------- launch ----------

extern "C" void kernel_launch(void* const* d_in, const int* in_sizes, int n_in,
                              void* d_out, int out_size, void* d_ws, size_t ws_size,
                              hipStream_t stream) {
    const float* x      = (const float*)d_in[0];   // [2,1024,4096] fp32
    const int*   w      = (const int*)d_in[1];     // [4096,4096] int, values in [-128,127]
    const float* scales = (const float*)d_in[2];   // [4096]
    const float* bias   = (const float*)d_in[3];   // [4096]
    float*       out    = (float*)d_out;           // [2,1024,4096] fp32

    int8_t* Aq = (int8_t*)d_ws;                                        // 8 MiB
    int8_t* Bq = (int8_t*)d_ws + (size_t)M_DIM * K_DIM;                // 16 MiB
    float*  sx = (float*)((int8_t*)d_ws + (size_t)(M_DIM + N_DIM) * K_DIM); // 8 KiB

    quant_x<<<M_DIM, 256, 0, stream>>>(x, Aq, sx);
    cvt_w8<<<(int)((size_t)N_DIM * K_DIM / 16 / 256), 256, 0, stream>>>(w, Bq);

    // 1-D grid of 256 blocks (16 bm x 16 bn), XCD-swizzled inside the kernel.
    gemm_bt_i8<<<256, 512, 0, stream>>>(Aq, Bq, sx, scales, bias, out);
}

// Round 8
// 168.752 us; speedup vs baseline: 1.2374x; 1.0038x over previous
//
#include <hip/hip_runtime.h>
#include <hip/hip_bf16.h>
#include <stdint.h>

// Shape fixed by reference: B=2, S=1024 -> M=2048; N=4096; K=4096
#define M_DIM 2048
#define N_DIM 4096
#define K_DIM 4096

#define BM 128
#define BN 256
#define BK 128            // int8 elements per K-tile = 128 B per row

#define ATILE (BM * BK)   // 16 KiB per A buffer
#define BTILE (BN * BK)   // 32 KiB per B buffer
#define NT (K_DIM / BK)   // 32 K-tiles

typedef __attribute__((ext_vector_type(4))) int   int4v;
typedef __attribute__((ext_vector_type(4))) float f32x4;

__device__ __forceinline__ void load_lds16(const void* g, void* l) {
    __builtin_amdgcn_global_load_lds(
        (const __attribute__((address_space(1))) void*)g,
        (__attribute__((address_space(3))) void*)l,
        16, 0, 0);
}

// ---------- x: fp32 [M,K] -> int8 per-row dynamic quant; sx[row] = rowmax/127 ----------
__global__ __launch_bounds__(256) void quant_x(const float* __restrict__ x,
                                               int8_t* __restrict__ Aq,
                                               float* __restrict__ sx) {
    const int row = blockIdx.x;
    const int tid = threadIdx.x;
    const float4* xr = (const float4*)(x + (size_t)row * K_DIM);

    float4 v[4];
    float mx = 0.f;
#pragma unroll
    for (int p = 0; p < 4; p++) {
        v[p] = xr[p * 256 + tid];
        mx = fmaxf(mx, fmaxf(fmaxf(fabsf(v[p].x), fabsf(v[p].y)),
                             fmaxf(fabsf(v[p].z), fabsf(v[p].w))));
    }
#pragma unroll
    for (int off = 32; off >= 1; off >>= 1)
        mx = fmaxf(mx, __shfl_xor(mx, off, 64));

    __shared__ float wmax[4];
    __shared__ float smax;
    if ((tid & 63) == 0) wmax[tid >> 6] = mx;
    __syncthreads();
    if (tid == 0) {
        float m = fmaxf(fmaxf(wmax[0], wmax[1]), fmaxf(wmax[2], wmax[3]));
        m = fmaxf(m, 1e-20f);
        smax = m;
        sx[row] = m * (1.0f / 127.0f);
    }
    __syncthreads();
    const float inv = 127.0f / smax;

    int* out = (int*)Aq + (size_t)row * (K_DIM / 4);
#pragma unroll
    for (int p = 0; p < 4; p++) {
        int q0 = (int)__builtin_rintf(v[p].x * inv);
        int q1 = (int)__builtin_rintf(v[p].y * inv);
        int q2 = (int)__builtin_rintf(v[p].z * inv);
        int q3 = (int)__builtin_rintf(v[p].w * inv);
        q0 = max(-127, min(127, q0)); q1 = max(-127, min(127, q1));
        q2 = max(-127, min(127, q2)); q3 = max(-127, min(127, q3));
        out[p * 256 + tid] = (q0 & 255) | ((q1 & 255) << 8) |
                             ((q2 & 255) << 16) | ((q3 & 255) << 24);
    }
}

// ---------- w: int32 [N,K] (values in [-128,127]) -> int8, exact narrowing ----------
__global__ __launch_bounds__(256) void cvt_w8(const int* __restrict__ w,
                                              int8_t* __restrict__ Bq) {
    size_t i = ((size_t)blockIdx.x * 256 + threadIdx.x) * 16;
    int4 a0 = *(const int4*)(w + i);
    int4 a1 = *(const int4*)(w + i + 4);
    int4 a2 = *(const int4*)(w + i + 8);
    int4 a3 = *(const int4*)(w + i + 12);
    uint4 t;
    t.x = (a0.x & 255) | ((a0.y & 255) << 8) | ((a0.z & 255) << 16) | ((a0.w & 255) << 24);
    t.y = (a1.x & 255) | ((a1.y & 255) << 8) | ((a1.z & 255) << 16) | ((a1.w & 255) << 24);
    t.z = (a2.x & 255) | ((a2.y & 255) << 8) | ((a2.z & 255) << 16) | ((a2.w & 255) << 24);
    t.w = (a3.x & 255) | ((a3.y & 255) << 8) | ((a3.z & 255) << 16) | ((a3.w & 255) << 24);
    *(uint4*)(Bq + i) = t;
}

// ---------- GEMM: C = Aq[M,K] x Bq[N,K]^T (i8 MFMA, i32 acc), epilogue dequant ----------
// r12: glds-throughput attack. Cross-round invariant (r4/r5/r6/r9/r11): duration
// tracks staged_bytes / (1.4-1.7 B/cyc per STAGING WAVE); LDS-read cuts and
// schedule surgery never moved it. Levers: staged bytes (tile area) and staging
// wave count. This kernel: (128,256) tile (staged total 512->384 MB; B staged 16x
// not 32x) AND 1024-thread block = 16 staging waves (r4's count) at grid 256.
// Decomposition: 16 waves = 8 spatial (2M x 4N, each 64x64 out, acc[4][4]) x
// 2-way K-split (ks = wave>>3 handles k-half ks*64 of each BK=128 tile) -- the
// r9-VERIFIED wave plan. Data path byte-identical to r4/r9: 128B rows, glds with
// XOR-swizzled source (phys colgroup p of row r holds global cg p^(r&7)), read
// cp = (ks*4+quad)^(l16&7) cancels to identity k-chunks, 2-way bank aliasing
// only (free, measured 0 conflicts). Structure = r4's simple loop: sync ->
// 3-glds burst (A 16KB, B 2x16KB; 1024thr x 16B = 16KB/instr) -> compute.
// LDS = A dbuf 32K + B dbuf 64K = 96 KiB, 1 block/CU, 16 waves/CU.
// K-split reduction: two 64KB LDS rounds (r9-verified math), then ks=0 stores.

__global__ __launch_bounds__(1024, 1) void gemm_bt_i8(
    const int8_t* __restrict__ A,      // [M,K] int8
    const int8_t* __restrict__ B,      // [N,K] int8
    const float*  __restrict__ sx,     // [M] row dequant scale
    const float*  __restrict__ scales, // [N]
    const float*  __restrict__ bias,   // [N]
    float* __restrict__ C)             // [M,N]
{
    __shared__ __align__(16) int8_t As[2 * ATILE];  // 32 KiB
    __shared__ __align__(16) int8_t Bs[2 * BTILE];  // 64 KiB

    const int tid  = threadIdx.x;

    // T1: XCD swizzle. 256 blocks = 8 chunks of 32; chunk = 4(bm) x 8(bn).
    const int bid   = blockIdx.x;
    const int xcd   = bid & 7;
    const int local = bid >> 3;                       // 0..31
    const int bm    = (xcd >> 1) * 4 + (local >> 3);  // 0..15
    const int bn    = (xcd & 1) * 8 + (local & 7);    // 0..15

    const int lane = tid & 63;
    const int wave = tid >> 6;           // 0..15
    const int spat = wave & 7;           // spatial 2x4
    const int ks   = wave >> 3;          // K-split half: 0 or 1
    const int wm   = (spat >> 2) * 64;   // 0 or 64
    const int wn   = (spat & 3) * 64;    // 0,64,128,192
    const int l16  = lane & 15;
    const int quad = lane >> 4;
    const int swz  = l16 & 7;
    // Fixed physical colgroup for this wave's k-half (r9 verified formula).
    const int cp   = (ks * 4 + quad) ^ swz;

    // Staging: 1024 thr x 16 B = 16 KiB per glds instr. A tile = 1 instr
    // (rows 0..127), B tile = 2 instrs (rows 0..127, 128..255). thread t ->
    // row = t>>3 (+128 for B seg1), phys colgroup = t&7; global colgroup =
    // phys ^ (row&7) [(128+r)&7 == r&7]. LDS byte addr = 16*t (linear, glds rule).
    const int srow = tid >> 3;           // 0..127
    const int cgl  = (tid & 7) ^ (srow & 7);

    const int8_t* ga  = A + (size_t)(bm * BM + srow)       * K_DIM + cgl * 16;
    const int8_t* gb0 = B + (size_t)(bn * BN + srow)       * K_DIM + cgl * 16;
    const int8_t* gb1 = B + (size_t)(bn * BN + 128 + srow) * K_DIM + cgl * 16;
    const int la = tid * 16;

#define STAGE(slot, k0_) do {                                                \
        load_lds16(ga  + (k0_), As + (slot) * ATILE + la);                   \
        load_lds16(gb0 + (k0_), Bs + (slot) * BTILE + la);                   \
        load_lds16(gb1 + (k0_), Bs + (slot) * BTILE + 16384 + la);           \
    } while (0)

    int4v acc[4][4] = {};

    // Prologue: stage tile 0 into buffer 0.
    STAGE(0, 0);

    for (int t = 0; t < NT; ++t) {
        __syncthreads();   // drains glds for buf[t&1]; all waves done with buf[(t&1)^1]

        if (t + 1 < NT)    // prefetch next tile, in flight during compute
            STAGE((t + 1) & 1, (t + 1) * BK);

        const int8_t* Ab = As + (t & 1) * ATILE;
        const int8_t* Bb = Bs + (t & 1) * BTILE;

        int4v af[4];
#pragma unroll
        for (int i = 0; i < 4; i++)
            af[i] = *(const int4v*)(Ab + (wm + i * 16 + l16) * BK + cp * 16);
#pragma unroll
        for (int j = 0; j < 4; j++) {
            int4v bf = *(const int4v*)(Bb + (wn + j * 16 + l16) * BK + cp * 16);
#pragma unroll
            for (int i = 0; i < 4; i++)
                acc[i][j] = __builtin_amdgcn_mfma_i32_16x16x64_i8(
                    af[i], bf, acc[i][j], 0, 0, 0);
        }
    }

#undef STAGE

    // ---- K-split reduction: ks=1 dumps acc to LDS, ks=0 adds. Two rounds of
    // 64 KB (4 spatial waves each) since 8 x 16KB exceeds the 96KB LDS. ----
    // Wave (spat&3) -> 16KB region: 0,1 -> As halves; 2,3 -> Bs first halves.
    int8_t* rbase = ((spat & 3) < 2 ? As : Bs) + (spat & 1) * 16384;

    __syncthreads();   // all K-loop LDS reads complete -> buffers reusable
    if (ks == 1 && spat < 4) {
#pragma unroll
        for (int i = 0; i < 4; i++)
#pragma unroll
            for (int j = 0; j < 4; j++)
                *(int4v*)(rbase + ((i * 4 + j) * 64 + lane) * 16) = acc[i][j];
    }
    __syncthreads();
    if (ks == 0 && spat < 4) {
#pragma unroll
        for (int i = 0; i < 4; i++)
#pragma unroll
            for (int j = 0; j < 4; j++)
                acc[i][j] += *(const int4v*)(rbase + ((i * 4 + j) * 64 + lane) * 16);
    }
    __syncthreads();
    if (ks == 1 && spat >= 4) {
#pragma unroll
        for (int i = 0; i < 4; i++)
#pragma unroll
            for (int j = 0; j < 4; j++)
                *(int4v*)(rbase + ((i * 4 + j) * 64 + lane) * 16) = acc[i][j];
    }
    __syncthreads();
    if (ks == 0 && spat >= 4) {
#pragma unroll
        for (int i = 0; i < 4; i++)
#pragma unroll
            for (int j = 0; j < 4; j++)
                acc[i][j] += *(const int4v*)(rbase + ((i * 4 + j) * 64 + lane) * 16);
    }

    if (ks == 0) {
        // Row dequant scales for this lane's 16 output rows.
        float sxr[16];
#pragma unroll
        for (int i = 0; i < 4; i++)
#pragma unroll
            for (int r = 0; r < 4; r++)
                sxr[i * 4 + r] = sx[bm * BM + wm + i * 16 + quad * 4 + r];

        // C/D layout (shape-determined, verified): col = lane&15, row = quad*4 + reg.
#pragma unroll
        for (int j = 0; j < 4; j++) {
            const int col = bn * BN + wn + j * 16 + l16;
            const float s = scales[col];
            const float b = bias[col];
#pragma unroll
            for (int i = 0; i < 4; i++) {
                const int row0 = bm * BM + wm + i * 16 + quad * 4;
#pragma unroll
                for (int r = 0; r < 4; r++) {
                    C[(size_t)(row0 + r) * N_DIM + col] =
                        (float)acc[i][j][r] * (sxr[i * 4 + r] * s) + b;
                }
            }
        }
    }
}

// ---------- launch ----------

extern "C" void kernel_launch(void* const* d_in, const int* in_sizes, int n_in,
                              void* d_out, int out_size, void* d_ws, size_t ws_size,
                              hipStream_t stream) {
    const float* x      = (const float*)d_in[0];   // [2,1024,4096] fp32
    const int*   w      = (const int*)d_in[1];     // [4096,4096] int, values in [-128,127]
    const float* scales = (const float*)d_in[2];   // [4096]
    const float* bias   = (const float*)d_in[3];   // [4096]
    float*       out    = (float*)d_out;           // [2,1024,4096] fp32

    int8_t* Aq = (int8_t*)d_ws;                                        // 8 MiB
    int8_t* Bq = (int8_t*)d_ws + (size_t)M_DIM * K_DIM;                // 16 MiB
    float*  sx = (float*)((int8_t*)d_ws + (size_t)(M_DIM + N_DIM) * K_DIM); // 8 KiB

    quant_x<<<M_DIM, 256, 0, stream>>>(x, Aq, sx);
    cvt_w8<<<(int)((size_t)N_DIM * K_DIM / 16 / 256), 256, 0, stream>>>(w, Bq);

    // 1-D grid of 256 blocks (16 bm x 16 bn), XCD-swizzled inside the kernel.
    gemm_bt_i8<<<256, 1024, 0, stream>>>(Aq, Bq, sx, scales, bias, out);
}